// Round 4
// baseline (1066.317 us; speedup 1.0000x reference)
//
#include <hip/hip_runtime.h>
#include <math.h>

// ---------------------------------------------------------------------------
// AttentionAggregator round 4:
//  - barrier-free MFMA flash attention (wave = 64 rows x 128 cols, ch split)
//  - software-pipelined: ap frags preloaded before next-iter S overwrites LDS
//  - LDS 36.8KB/block (2-pass proj epilogue) + launch_bounds(256,3) -> 3 blk/CU
//  - NSPLIT=8 -> 1024 blocks
//  - gather via LDS transpose: coalesced reads AND writes
// ---------------------------------------------------------------------------
#define NR 8192
#define DQ 32
#define DV 256
#define OUT_DIM 64
#define NSPLIT 8
#define BK 64
#define NIT ((NR / NSPLIT) / BK)      // 16
// 2^-1.25 * sqrt(log2(e)): qh = q*QS2 -> dot = (q.q')/sqrt(32)*log2(e); p=2^s
#define QSCALE2 0.5050114839784955f

typedef short short8 __attribute__((ext_vector_type(8)));   // 8 bf16
typedef float f32x16 __attribute__((ext_vector_type(16)));  // 32x32 MFMA acc

__device__ __forceinline__ unsigned short f32_to_bf16(float f) {
    union { float f; unsigned int u; } v; v.f = f;
    unsigned int u = v.u + 0x7FFFu + ((v.u >> 16) & 1u);    // RNE
    return (unsigned short)(u >> 16);
}
__device__ __forceinline__ float exp2_fast(float x) {
#if __has_builtin(__builtin_amdgcn_exp2f)
    return __builtin_amdgcn_exp2f(x);
#else
    return __expf(x * 0.6931471805599453f);
#endif
}

// ---------------------------------------------------------------------------
__global__ void zero_kernel(float4* __restrict__ p) {
    p[blockIdx.x * blockDim.x + threadIdx.x] = make_float4(0.f, 0.f, 0.f, 0.f);
}

__global__ void qconv_kernel(const float* __restrict__ user,
                             const float* __restrict__ item,
                             unsigned short* __restrict__ qh) {
    int side = blockIdx.y;
    int i = blockIdx.x * blockDim.x + threadIdx.x;
    const float* src = side ? item : user;
    qh[(size_t)side * NR * DQ + i] = f32_to_bf16(src[i] * QSCALE2);
}

// wbf[wm][ch][kt8][nt][lane64][8] = W[ch*128 + kt8*16 + (lane>>5)*8 + i][nt*32 + (lane&31)]
__global__ void wconv_kernel(const float* __restrict__ Wu,
                             const float* __restrict__ Wi,
                             unsigned short* __restrict__ wbf) {
    int g  = blockIdx.x * blockDim.x + threadIdx.x;   // 0..4095
    int ln = g & 31, h = (g >> 5) & 1, nt = (g >> 6) & 1;
    int kt = (g >> 7) & 7, ch = (g >> 10) & 1, wm = g >> 11;
    const float* W = wm ? Wi : Wu;
    unsigned short* dst = wbf + (size_t)g * 8;
#pragma unroll
    for (int i = 0; i < 8; ++i) {
        int k = ch * 128 + kt * 16 + h * 8 + i;
        dst[i] = f32_to_bf16(W[k * OUT_DIM + nt * 32 + ln]);
    }
}

// ---------------------------------------------------------------------------
// Gather via LDS transpose. Block = one side x 64 keys. Phase 1: coalesced
// 32B row reads -> bf16 LDS tile T[64][264]. Phase 2: coalesced 16B vt writes.
// vt layout (same as R3): vt[(side*2+ch)] + kt*2048 + ct*512 + lane*8 + i
//   holds V[kt*16 + (lane>>5)*8 + i][ch*128 + ct*32 + (lane&31)]
// ---------------------------------------------------------------------------
__global__ void gather_vt_kernel(const float* __restrict__ review,
                                 const float* __restrict__ user,
                                 const float* __restrict__ item,
                                 const int* __restrict__ adj_ur, const int* __restrict__ adj_ri,
                                 const int* __restrict__ adj_ir, const int* __restrict__ adj_ru,
                                 unsigned short* __restrict__ vt) {
    const int side = blockIdx.y;
    const int key0 = blockIdx.x * 64;
    const int t = threadIdx.x;
    __shared__ __align__(16) unsigned short T[64][264];   // 33.8 KB
    const int* adjA   = side ? adj_ir : adj_ur;
    const int* adjB   = side ? adj_ru : adj_ri;
    const float* srcB = side ? user : item;

    // phase 1: thread (key = t>>2, q = t&3) loads segments 2q, 2q+1 (32 floats each)
    {
        int key = t >> 2, q = t & 3;
#pragma unroll
        for (int rr = 0; rr < 2; ++rr) {
            int ss  = q * 2 + rr;         // segment 0..7
            int knb = ss >> 1, isB = ss & 1;
            int row = (isB ? adjB : adjA)[(key0 + key) * 4 + knb];
            const float4* src = (const float4*)((isB ? srcB : review) + (size_t)row * DQ);
            int dbase = knb * 64 + isB * 32;
#pragma unroll
            for (int d = 0; d < 4; ++d) {
                float4 a = src[d * 2], b = src[d * 2 + 1];
                short8 v;
                v[0] = (short)f32_to_bf16(a.x); v[1] = (short)f32_to_bf16(a.y);
                v[2] = (short)f32_to_bf16(a.z); v[3] = (short)f32_to_bf16(a.w);
                v[4] = (short)f32_to_bf16(b.x); v[5] = (short)f32_to_bf16(b.y);
                v[6] = (short)f32_to_bf16(b.z); v[7] = (short)f32_to_bf16(b.w);
                *(short8*)&T[key][dbase + d * 8] = v;
            }
        }
    }
    __syncthreads();

    // phase 2: 8 coalesced short8 writes per thread
#pragma unroll
    for (int w8 = 0; w8 < 8; ++w8) {
        int u    = t + 256 * w8;          // 0..2047
        int lane = u & 63;
        int ct   = (u >> 6) & 3;
        int ch   = (u >> 8) & 1;
        int ktl  = u >> 9;                // 0..3
        int ln = lane & 31, h = lane >> 5;
        int c = ch * 128 + ct * 32 + ln;
        short8 v;
#pragma unroll
        for (int i = 0; i < 8; ++i)
            v[i] = (short)T[ktl * 16 + h * 8 + i][c];
        size_t ktg = (size_t)blockIdx.x * 4 + ktl;
        size_t dst = ((size_t)(side * 2 + ch)) * NR * 128 + ktg * 2048
                   + (size_t)ct * 512 + (size_t)lane * 8;
        *(short8*)(vt + dst) = v;
    }
}

// ---------------------------------------------------------------------------
// Pipelined barrier-free flash attention + fused projection.
// bx: side=bx&1, ch=(bx>>1)&1, sp=(bx>>2)&7, rb=bx>>5.  1024 blocks x 4 waves.
// Loop k: [preload ap frags of P(k)] -> [S-phase builds P(k+1), overwriting
// LDS after the reads (per-wave in-order DS + explicit lgkmcnt(0))] ->
// [PV MFMAs of iter k]. The ds_read->MFMA chain is hidden by a full iter.
// ---------------------------------------------------------------------------
__global__ __launch_bounds__(256, 3) void flash_kernel(
        const unsigned short* __restrict__ qh,
        const unsigned short* __restrict__ vt,
        const unsigned short* __restrict__ wbf,
        float* __restrict__ acc,     // [2][NR][64]
        float* __restrict__ lsum)    // [2][NR]
{
    const int bx   = blockIdx.x;
    const int side = bx & 1;
    const int ch   = (bx >> 1) & 1;
    const int sp   = (bx >> 2) & (NSPLIT - 1);
    const int rb   = bx >> 5;                  // 0..31
    const int w    = threadIdx.x >> 6;
    const int lane = threadIdx.x & 63;
    const int ln   = lane & 31;
    const int h    = lane >> 5;

    const int m0 = rb * 256 + w * 64;
    const unsigned short* Q  = qh + (size_t)side * NR * DQ;
    const unsigned short* VT = vt + ((size_t)(side * 2 + ch)) * NR * 128;

    __shared__ __align__(16) unsigned short Sbuf[4][64 * 72];  // 36864 B
    unsigned short* Pw = Sbuf[w];

    short8 aq[2][2];
#pragma unroll
    for (int mt = 0; mt < 2; ++mt)
#pragma unroll
        for (int dh = 0; dh < 2; ++dh)
            aq[mt][dh] = *(const short8*)(Q + (size_t)(m0 + mt * 32 + ln) * DQ + dh * 16 + h * 8);

    short8 bones;
#pragma unroll
    for (int i = 0; i < 8; ++i) bones[i] = (short)0x3F80;

    f32x16 zf;
#pragma unroll
    for (int r = 0; r < 16; ++r) zf[r] = 0.f;
    f32x16 o[2][4];
#pragma unroll
    for (int mt = 0; mt < 2; ++mt)
#pragma unroll
        for (int ct = 0; ct < 4; ++ct) o[mt][ct] = zf;
    f32x16 l0 = zf, l1 = zf;

    const int j_begin = sp * (NR / NSPLIT);

    // S-phase: compute P(j0) into Pw. do_wait=1 inserts lgkmcnt(0) before the
    // first LDS overwrite so preloaded ap frags are guaranteed landed.
    auto s_phase = [&](int j0, int do_wait) {
#pragma unroll
        for (int kt = 0; kt < 2; ++kt) {
            const unsigned short* kbp = Q + (size_t)(j0 + kt * 32 + ln) * DQ + h * 8;
            short8 bq0 = *(const short8*)(kbp);
            short8 bq1 = *(const short8*)(kbp + 16);
            f32x16 s0 = __builtin_amdgcn_mfma_f32_32x32x16_bf16(aq[0][0], bq0, zf, 0, 0, 0);
            s0 = __builtin_amdgcn_mfma_f32_32x32x16_bf16(aq[0][1], bq1, s0, 0, 0, 0);
            f32x16 s1 = __builtin_amdgcn_mfma_f32_32x32x16_bf16(aq[1][0], bq0, zf, 0, 0, 0);
            s1 = __builtin_amdgcn_mfma_f32_32x32x16_bf16(aq[1][1], bq1, s1, 0, 0, 0);
            unsigned short pb0[16], pb1[16];
#pragma unroll
            for (int r = 0; r < 16; ++r) {
                pb0[r] = f32_to_bf16(exp2_fast(s0[r]));
                pb1[r] = f32_to_bf16(exp2_fast(s1[r]));
            }
            if (do_wait && kt == 0) __builtin_amdgcn_s_waitcnt(0xC07F);  // lgkmcnt(0)
#pragma unroll
            for (int r = 0; r < 16; ++r) {
                int row = (r & 3) + ((r >> 2) << 3) + h * 4;
                Pw[row * 72 + kt * 32 + ln]        = pb0[r];
                Pw[(32 + row) * 72 + kt * 32 + ln] = pb1[r];
            }
        }
    };

    s_phase(j_begin, 0);   // prologue: P(0)

    for (int it = 0; it < NIT; ++it) {
        // ---- preload all ap frags of P(it) ----
        short8 ap0[4], ap1[4];
#pragma unroll
        for (int ks = 0; ks < 4; ++ks) {
            ap0[ks] = *(const short8*)&Pw[ln * 72 + ks * 16 + h * 8];
            ap1[ks] = *(const short8*)&Pw[(32 + ln) * 72 + ks * 16 + h * 8];
        }
        // ---- S-phase for it+1 (overwrites Pw; reads above are in-order-safe) ----
        if (it + 1 < NIT) s_phase(j_begin + (it + 1) * BK, 1);

        // ---- PV MFMAs for it ----
        const int kt0 = (j_begin + it * BK) >> 4;
#pragma unroll
        for (int ks = 0; ks < 4; ++ks) {
            const unsigned short* vb = VT + (size_t)(kt0 + ks) * 2048 + (size_t)lane * 8;
            l0 = __builtin_amdgcn_mfma_f32_32x32x16_bf16(ap0[ks], bones, l0, 0, 0, 0);
            l1 = __builtin_amdgcn_mfma_f32_32x32x16_bf16(ap1[ks], bones, l1, 0, 0, 0);
#pragma unroll
            for (int ct = 0; ct < 4; ++ct) {
                short8 bv = *(const short8*)(vb + ct * 512);
                o[0][ct] = __builtin_amdgcn_mfma_f32_32x32x16_bf16(ap0[ks], bv, o[0][ct], 0, 0, 0);
                o[1][ct] = __builtin_amdgcn_mfma_f32_32x32x16_bf16(ap1[ks], bv, o[1][ct], 0, 0, 0);
            }
        }
    }

    // ---- epilogue: 2-pass (64 cols each) O->LDS->A-frags, proj MFMA ----
    f32x16 pp[2][2];
    pp[0][0] = zf; pp[0][1] = zf; pp[1][0] = zf; pp[1][1] = zf;
    const unsigned short* wb_base = wbf + ((size_t)(side * 2 + ch) * 8) * 1024;
#pragma unroll
    for (int p = 0; p < 2; ++p) {
        __builtin_amdgcn_s_waitcnt(0xC07F);  // prior reads of Pw landed
#pragma unroll
        for (int mt = 0; mt < 2; ++mt)
#pragma unroll
            for (int c2 = 0; c2 < 2; ++c2)
#pragma unroll
                for (int r = 0; r < 16; ++r) {
                    int row = mt * 32 + (r & 3) + ((r >> 2) << 3) + h * 4;
                    Pw[row * 72 + c2 * 32 + ln] = f32_to_bf16(o[mt][2 * p + c2][r]);
                }
#pragma unroll
        for (int ktl = 0; ktl < 4; ++ktl) {
            short8 a0 = *(const short8*)&Pw[ln * 72 + ktl * 16 + h * 8];
            short8 a1 = *(const short8*)&Pw[(32 + ln) * 72 + ktl * 16 + h * 8];
            int kt8 = p * 4 + ktl;
#pragma unroll
            for (int nt = 0; nt < 2; ++nt) {
                short8 bw = *(const short8*)(wb_base + (size_t)kt8 * 1024 + nt * 512 + (size_t)lane * 8);
                pp[0][nt] = __builtin_amdgcn_mfma_f32_32x32x16_bf16(a0, bw, pp[0][nt], 0, 0, 0);
                pp[1][nt] = __builtin_amdgcn_mfma_f32_32x32x16_bf16(a1, bw, pp[1][nt], 0, 0, 0);
            }
        }
    }

    // ---- atomic accumulate projected partials + denominators ----
#pragma unroll
    for (int mt = 0; mt < 2; ++mt)
#pragma unroll
        for (int nt = 0; nt < 2; ++nt)
#pragma unroll
            for (int r = 0; r < 16; ++r) {
                int row = (r & 3) + ((r >> 2) << 3) + h * 4;
                int gm  = m0 + mt * 32 + row;
                atomicAdd(&acc[((size_t)side * NR + gm) * OUT_DIM + nt * 32 + ln],
                          pp[mt][nt][r]);
            }
    if (ch == 0 && ln == 0) {
#pragma unroll
        for (int r = 0; r < 16; ++r) {
            int row = (r & 3) + ((r >> 2) << 3) + h * 4;
            atomicAdd(&lsum[(size_t)side * NR + m0 + row], l0[r]);
            atomicAdd(&lsum[(size_t)side * NR + m0 + 32 + row], l1[r]);
        }
    }
}

// ---------------------------------------------------------------------------
__global__ void final_kernel(const float* __restrict__ acc,
                             const float* __restrict__ lsum,
                             float* __restrict__ out) {
    int tid = blockIdx.x * blockDim.x + threadIdx.x;
    int row = tid >> 6;
    out[tid] = fmaxf(acc[tid] / lsum[row], 0.f);
}

// ---------------------------------------------------------------------------
extern "C" void kernel_launch(void* const* d_in, const int* in_sizes, int n_in,
                              void* d_out, int out_size, void* d_ws, size_t ws_size,
                              hipStream_t stream) {
    const float* review = (const float*)d_in[0];
    const float* user   = (const float*)d_in[1];
    const float* item   = (const float*)d_in[2];
    const int* adj_ur   = (const int*)d_in[3];
    const int* adj_ri   = (const int*)d_in[4];
    const int* adj_ir   = (const int*)d_in[5];
    const int* adj_ru   = (const int*)d_in[6];
    const float* Wu     = (const float*)d_in[7];
    const float* Wi     = (const float*)d_in[8];
    float* out = (float*)d_out;

    // ws: acc | lsum | vt | qh | wbf  (13.3 MB)
    float* acc  = (float*)d_ws;
    float* lsum = acc + (size_t)2 * NR * OUT_DIM;
    unsigned short* vt  = (unsigned short*)(lsum + 2 * NR);
    unsigned short* qh  = vt + (size_t)4 * NR * 128;
    unsigned short* wbf = qh + (size_t)2 * NR * DQ;

    int zero_f4 = (2 * NR * OUT_DIM + 2 * NR) / 4;
    zero_kernel<<<zero_f4 / 256, 256, 0, stream>>>((float4*)acc);
    qconv_kernel<<<dim3(NR * DQ / 256, 2), 256, 0, stream>>>(user, item, qh);
    wconv_kernel<<<16, 256, 0, stream>>>(Wu, Wi, wbf);
    gather_vt_kernel<<<dim3(NR / 64, 2), 256, 0, stream>>>(
        review, user, item, adj_ur, adj_ri, adj_ir, adj_ru, vt);
    flash_kernel<<<2 * 2 * NSPLIT * (NR / 256), 256, 0, stream>>>(qh, vt, wbf, acc, lsum);
    final_kernel<<<2 * NR * OUT_DIM / 256, 256, 0, stream>>>(acc, lsum, out);
}

// Round 5
// 244.441 us; speedup vs baseline: 4.3623x; 4.3623x over previous
//
#include <hip/hip_runtime.h>
#include <math.h>

// ---------------------------------------------------------------------------
// AttentionAggregator round 5:
//  - wave tile 32 rows x 256 cols (NO column split -> zero duplicated S/exp)
//  - software-pipelined barrier-free K-loop (ap preload before next S-phase)
//  - P stored as packed b32 (key-permuted layout; vt/wbf use same permutation
//    so ds_read_b128 A-frags stay contiguous)
//  - l (softmax denom) as VALU per-lane partials + one end shuffle-reduce
//  - launch_bounds(256,2): R4 showed (256,3) spills acc file to scratch
//    (VGPR 84, 4.9GB HBM) -- 2 waves/SIMD is this kernel's ceiling.
//  - NSPLIT=4 -> 512 blocks = exactly 2 resident/CU, one pass
// ---------------------------------------------------------------------------
#define NR 8192
#define DQ 32
#define DV 256
#define OUT_DIM 64
#define NSPLIT 4
#define BK 64
#define NIT ((NR / NSPLIT) / BK)      // 32
// 2^-1.25 * sqrt(log2(e)): qh = q*QS2 -> dot = (q.q')/sqrt(32)*log2(e); p=2^s
#define QSCALE2 0.5050114839784955f

typedef short short8 __attribute__((ext_vector_type(8)));   // 8 bf16
typedef float f32x16 __attribute__((ext_vector_type(16)));  // 32x32 MFMA acc

__device__ __forceinline__ unsigned short f32_to_bf16(float f) {
    union { float f; unsigned int u; } v; v.f = f;
    unsigned int u = v.u + 0x7FFFu + ((v.u >> 16) & 1u);    // RNE
    return (unsigned short)(u >> 16);
}
__device__ __forceinline__ float exp2_fast(float x) {
#if __has_builtin(__builtin_amdgcn_exp2f)
    return __builtin_amdgcn_exp2f(x);
#else
    return exp2f(x);
#endif
}

// ---------------------------------------------------------------------------
__global__ void zero_kernel(float4* __restrict__ p) {
    p[blockIdx.x * blockDim.x + threadIdx.x] = make_float4(0.f, 0.f, 0.f, 0.f);
}

__global__ void qconv_kernel(const float* __restrict__ user,
                             const float* __restrict__ item,
                             unsigned short* __restrict__ qh) {
    int side = blockIdx.y;
    int i = blockIdx.x * blockDim.x + threadIdx.x;
    const float* src = side ? item : user;
    qh[(size_t)side * NR * DQ + i] = f32_to_bf16(src[i] * QSCALE2);
}

// wbf[wm][p4][kt4][nt2][lane64][i8] = W[p*64 + kt*16 + h*8 + i][nt*32 + ln]
// (natural k within frag: epilogue LDS store is row-major, reads contiguous)
__global__ void wconv_kernel(const float* __restrict__ Wu,
                             const float* __restrict__ Wi,
                             unsigned short* __restrict__ wbf) {
    int g  = blockIdx.x * blockDim.x + threadIdx.x;   // 0..4095
    int ln = g & 31, h = (g >> 5) & 1, nt = (g >> 6) & 1;
    int kt = (g >> 7) & 3, p = (g >> 9) & 3, wm = g >> 11;
    const float* W = wm ? Wi : Wu;
    unsigned short* dst = wbf + (size_t)g * 8;
#pragma unroll
    for (int i = 0; i < 8; ++i) {
        int k = p * 64 + kt * 16 + h * 8 + i;
        dst[i] = f32_to_bf16(W[k * OUT_DIM + nt * 32 + ln]);
    }
}

// ---------------------------------------------------------------------------
// Gather via LDS transpose into PERMUTED frag-native vt.
// B-frag position (tile g16, ct, lane=(ln,h), reg i) holds
//   V[logical key = (g16>>2)*64 + (i&1)*32 + (g16&3)*8 + h*4 + (i>>1)]
//    [col = ct*32 + ln]
// matching flash's packed-b32 P layout (P short offset o=ks*16+h*8+i maps to
// S-key (kt=o&1, c=o>>1) -> local key (o&1)*32 + (o>>1)).
// Block = one side x 64 keys (= 4 vt tiles). Phase 1: coalesced 32B row reads
// -> bf16 LDS tile T[64][264]. Phase 2: coalesced 16B vt writes.
// ---------------------------------------------------------------------------
__global__ void gather_vt_kernel(const float* __restrict__ review,
                                 const float* __restrict__ user,
                                 const float* __restrict__ item,
                                 const int* __restrict__ adj_ur, const int* __restrict__ adj_ri,
                                 const int* __restrict__ adj_ir, const int* __restrict__ adj_ru,
                                 unsigned short* __restrict__ vt) {
    const int side = blockIdx.y;
    const int key0 = blockIdx.x * 64;
    const int t = threadIdx.x;
    __shared__ __align__(16) unsigned short T[64][264];   // 33.8 KB
    const int* adjA   = side ? adj_ir : adj_ur;
    const int* adjB   = side ? adj_ru : adj_ri;
    const float* srcB = side ? user : item;

    // phase 1: thread (key = t>>2, q = t&3) loads segments 2q, 2q+1
    {
        int key = t >> 2, q = t & 3;
#pragma unroll
        for (int rr = 0; rr < 2; ++rr) {
            int ss  = q * 2 + rr;
            int knb = ss >> 1, isB = ss & 1;
            int row = (isB ? adjB : adjA)[(key0 + key) * 4 + knb];
            const float4* src = (const float4*)((isB ? srcB : review) + (size_t)row * DQ);
            int dbase = knb * 64 + isB * 32;
#pragma unroll
            for (int d = 0; d < 4; ++d) {
                float4 a = src[d * 2], b = src[d * 2 + 1];
                short8 v;
                v[0] = (short)f32_to_bf16(a.x); v[1] = (short)f32_to_bf16(a.y);
                v[2] = (short)f32_to_bf16(a.z); v[3] = (short)f32_to_bf16(a.w);
                v[4] = (short)f32_to_bf16(b.x); v[5] = (short)f32_to_bf16(b.y);
                v[6] = (short)f32_to_bf16(b.z); v[7] = (short)f32_to_bf16(b.w);
                *(short8*)&T[key][dbase + d * 8] = v;
            }
        }
    }
    __syncthreads();

    // phase 2: 8 coalesced short8 writes per thread, permuted key order
#pragma unroll
    for (int w8 = 0; w8 < 8; ++w8) {
        int u    = t + 256 * w8;          // 0..2047
        int lane = u & 63;
        int ct   = (u >> 6) & 7;
        int ktl  = u >> 9;                // 0..3 (tile within 64-key group)
        int ln = lane & 31, h = lane >> 5;
        int col = ct * 32 + ln;
        short8 v;
#pragma unroll
        for (int i = 0; i < 8; ++i) {
            int lkey = (i & 1) * 32 + ktl * 8 + h * 4 + (i >> 1);
            v[i] = (short)T[lkey][col];
        }
        size_t dst = (size_t)side * NR * DV
                   + ((size_t)blockIdx.x * 4 + ktl) * 4096
                   + (size_t)ct * 512 + (size_t)lane * 8;
        *(short8*)(vt + dst) = v;
    }
}

// ---------------------------------------------------------------------------
// Pipelined barrier-free flash attention + fused projection.
// bx: side=bx&1, sp=(bx>>1)&3, rb=bx>>3 (0..63). 512 blocks x 4 waves.
// Wave: 32 rows x 256 cols x 2048 keys. Per 64-key iter:
//   [preload 4 ap b128 frags of P(it)] -> [S-phase builds P(it+1): 4 MFMA,
//   32 exp, 16 packed b32 LDS writes] -> [PV: 32 MFMA, bv from global].
// ---------------------------------------------------------------------------
__global__ __launch_bounds__(256, 2) void flash_kernel(
        const unsigned short* __restrict__ qh,
        const unsigned short* __restrict__ vt,
        const unsigned short* __restrict__ wbf,
        float* __restrict__ acc,     // [2][NR][64]
        float* __restrict__ lsum)    // [2][NR]
{
    const int bx   = blockIdx.x;
    const int side = bx & 1;
    const int sp   = (bx >> 1) & (NSPLIT - 1);
    const int rb   = bx >> 3;                  // 0..63
    const int w    = threadIdx.x >> 6;
    const int lane = threadIdx.x & 63;
    const int ln   = lane & 31;
    const int h    = lane >> 5;

    const int m0 = rb * 128 + w * 32;
    const unsigned short* Q  = qh + (size_t)side * NR * DQ;
    const unsigned short* VT = vt + (size_t)side * NR * DV;

    // wave-private P: 32 rows x 72 shorts (144B rows: 16B-aligned b128 reads,
    // conflict-free measured in R3). Packed writes use uint view (36/row).
    __shared__ __align__(16) unsigned short Sbuf[4][32 * 72];  // 18.4 KB
    unsigned short* Pw = Sbuf[w];
    unsigned int* Pw32 = (unsigned int*)Pw;

    // persistent Q A-frag (32 rows): A[m=ln][k=h*8+i (+16 dh)]
    short8 aq[2];
#pragma unroll
    for (int dh = 0; dh < 2; ++dh)
        aq[dh] = *(const short8*)(Q + (size_t)(m0 + ln) * DQ + dh * 16 + h * 8);

    f32x16 zf;
#pragma unroll
    for (int r = 0; r < 16; ++r) zf[r] = 0.f;
    f32x16 o[8];
#pragma unroll
    for (int ct = 0; ct < 8; ++ct) o[ct] = zf;
    float l_part[16];
#pragma unroll
    for (int r = 0; r < 16; ++r) l_part[r] = 0.f;

    const int j_begin = sp * (NR / NSPLIT);

    // S-phase: P(j0) -> Pw. Packs (kt0,kt1) exp pairs into one b32/row/lane.
    auto s_phase = [&](int j0, int do_wait) {
        const unsigned short* kb0 = Q + (size_t)(j0 + ln) * DQ + h * 8;
        const unsigned short* kb1 = Q + (size_t)(j0 + 32 + ln) * DQ + h * 8;
        short8 b00 = *(const short8*)(kb0);
        short8 b01 = *(const short8*)(kb0 + 16);
        short8 b10 = *(const short8*)(kb1);
        short8 b11 = *(const short8*)(kb1 + 16);
        f32x16 s0 = __builtin_amdgcn_mfma_f32_32x32x16_bf16(aq[0], b00, zf, 0, 0, 0);
        s0 = __builtin_amdgcn_mfma_f32_32x32x16_bf16(aq[1], b01, s0, 0, 0, 0);
        f32x16 s1 = __builtin_amdgcn_mfma_f32_32x32x16_bf16(aq[0], b10, zf, 0, 0, 0);
        s1 = __builtin_amdgcn_mfma_f32_32x32x16_bf16(aq[1], b11, s1, 0, 0, 0);
        if (do_wait) __builtin_amdgcn_s_waitcnt(0xC07F);  // lgkmcnt(0): ap landed
#pragma unroll
        for (int r = 0; r < 16; ++r) {
            float e0 = exp2_fast(s0[r]);
            float e1 = exp2_fast(s1[r]);
            l_part[r] += e0 + e1;
            // pack bf16(e0) | bf16(e1)<<16 (round-half-up) via v_perm
            unsigned int u0 = __builtin_bit_cast(unsigned int, e0) + 0x8000u;
            unsigned int u1 = __builtin_bit_cast(unsigned int, e1) + 0x8000u;
            unsigned int pk = __builtin_amdgcn_perm(u1, u0, 0x07060302);
            int row = (r & 3) + ((r >> 2) << 3) + h * 4;
            Pw32[row * 36 + ln] = pk;
        }
    };

    s_phase(j_begin, 0);   // prologue

    for (int it = 0; it < NIT; ++it) {
        // preload all 4 ap frags of P(it): A[m=ln][k'=ks*16+h*8+i]
        short8 ap[4];
#pragma unroll
        for (int ks = 0; ks < 4; ++ks)
            ap[ks] = *(const short8*)&Pw[ln * 72 + ks * 16 + h * 8];

        if (it + 1 < NIT) s_phase(j_begin + (it + 1) * BK, 1);

        const int g16 = (j_begin + it * BK) >> 4;
#pragma unroll
        for (int ks = 0; ks < 4; ++ks) {
            const unsigned short* vb = VT + (size_t)(g16 + ks) * 4096 + (size_t)lane * 8;
#pragma unroll
            for (int ct = 0; ct < 8; ++ct) {
                short8 bv = *(const short8*)(vb + ct * 512);
                o[ct] = __builtin_amdgcn_mfma_f32_32x32x16_bf16(ap[ks], bv, o[ct], 0, 0, 0);
            }
        }
    }

    // ---- l: reduce per-lane partials across the 32 key-lanes of each half ----
#pragma unroll
    for (int r = 0; r < 16; ++r) {
        float v = l_part[r];
        v += __shfl_xor(v, 1);
        v += __shfl_xor(v, 2);
        v += __shfl_xor(v, 4);
        v += __shfl_xor(v, 8);
        v += __shfl_xor(v, 16);
        l_part[r] = v;
    }
    if (ln == 0) {
#pragma unroll
        for (int r = 0; r < 16; ++r) {
            int row = (r & 3) + ((r >> 2) << 3) + h * 4;
            atomicAdd(&lsum[(size_t)side * NR + m0 + row], l_part[r]);
        }
    }

    // ---- epilogue: 4 passes of 64 cols: O->bf16->LDS row-major, proj MFMA ----
    f32x16 pp[2];
    pp[0] = zf; pp[1] = zf;
    const unsigned short* wb_base = wbf + (size_t)side * 16384;
#pragma unroll
    for (int p = 0; p < 4; ++p) {
        __builtin_amdgcn_s_waitcnt(0xC07F);
#pragma unroll
        for (int c2 = 0; c2 < 2; ++c2)
#pragma unroll
            for (int r = 0; r < 16; ++r) {
                int row = (r & 3) + ((r >> 2) << 3) + h * 4;
                Pw[row * 72 + c2 * 32 + ln] = f32_to_bf16(o[2 * p + c2][r]);
            }
#pragma unroll
        for (int kt = 0; kt < 4; ++kt) {
            short8 a = *(const short8*)&Pw[ln * 72 + kt * 16 + h * 8];
#pragma unroll
            for (int nt = 0; nt < 2; ++nt) {
                short8 bw = *(const short8*)(wb_base
                            + ((size_t)(p * 4 + kt) * 2 + nt) * 512 + (size_t)lane * 8);
                pp[nt] = __builtin_amdgcn_mfma_f32_32x32x16_bf16(a, bw, pp[nt], 0, 0, 0);
            }
        }
    }

    // ---- atomic accumulate projected partials ----
#pragma unroll
    for (int nt = 0; nt < 2; ++nt)
#pragma unroll
        for (int r = 0; r < 16; ++r) {
            int row = (r & 3) + ((r >> 2) << 3) + h * 4;
            atomicAdd(&acc[((size_t)side * NR + m0 + row) * OUT_DIM + nt * 32 + ln],
                      pp[nt][r]);
        }
}

// ---------------------------------------------------------------------------
__global__ void final_kernel(const float* __restrict__ acc,
                             const float* __restrict__ lsum,
                             float* __restrict__ out) {
    int tid = blockIdx.x * blockDim.x + threadIdx.x;
    int row = tid >> 6;
    out[tid] = fmaxf(acc[tid] / lsum[row], 0.f);
}

// ---------------------------------------------------------------------------
extern "C" void kernel_launch(void* const* d_in, const int* in_sizes, int n_in,
                              void* d_out, int out_size, void* d_ws, size_t ws_size,
                              hipStream_t stream) {
    const float* review = (const float*)d_in[0];
    const float* user   = (const float*)d_in[1];
    const float* item   = (const float*)d_in[2];
    const int* adj_ur   = (const int*)d_in[3];
    const int* adj_ri   = (const int*)d_in[4];
    const int* adj_ir   = (const int*)d_in[5];
    const int* adj_ru   = (const int*)d_in[6];
    const float* Wu     = (const float*)d_in[7];
    const float* Wi     = (const float*)d_in[8];
    float* out = (float*)d_out;

    // ws: acc | lsum | vt | qh | wbf  (~13.2 MB)
    float* acc  = (float*)d_ws;
    float* lsum = acc + (size_t)2 * NR * OUT_DIM;
    unsigned short* vt  = (unsigned short*)(lsum + 2 * NR);
    unsigned short* qh  = vt + (size_t)2 * NR * DV;
    unsigned short* wbf = qh + (size_t)2 * NR * DQ;

    int zero_f4 = (2 * NR * OUT_DIM + 2 * NR) / 4;
    zero_kernel<<<zero_f4 / 256, 256, 0, stream>>>((float4*)acc);
    qconv_kernel<<<dim3(NR * DQ / 256, 2), 256, 0, stream>>>(user, item, qh);
    wconv_kernel<<<16, 256, 0, stream>>>(Wu, Wi, wbf);
    gather_vt_kernel<<<dim3(NR / 64, 2), 256, 0, stream>>>(
        review, user, item, adj_ur, adj_ri, adj_ir, adj_ru, vt);
    flash_kernel<<<2 * NSPLIT * (NR / 128), 256, 0, stream>>>(qh, vt, wbf, acc, lsum);
    final_kernel<<<2 * NR * OUT_DIM / 256, 256, 0, stream>>>(acc, lsum, out);
}

// Round 6
// 174.471 us; speedup vs baseline: 6.1117x; 1.4010x over previous
//
#include <hip/hip_runtime.h>
#include <math.h>

// ---------------------------------------------------------------------------
// AttentionAggregator round 6:
//  R5 post-mortem: MFMA busy 32us (= issue floor) but 2GB of per-wave global
//  V reads -> L3-BW bound at ~12.6 TB/s. Fix: share V tiles across 8 waves
//  via LDS (global_load_lds, double-buffered): V global traffic 2GB -> 256MB,
//  XCD-affine (bx&7 = side+2*sp) -> L2-resident.
//  - block 512 thr (8 waves), 256 blocks, 1/CU; wave = 32 rows x 256 cols.
//  - one __syncthreads/iter; DMA issued a full iter before the barrier that
//    needs it -> drain is cheap. kb loads issued BEFORE staging DMA so the
//    S-MFMA waitcnt keeps staging in flight.
//  - launch_bounds(512,2): 256 unified regs/wave (R4 proved tighter spills).
//  - prep merges zero+qconv+wconv (6 -> 4 launches).
// ---------------------------------------------------------------------------
#define NR 8192
#define DQ 32
#define DV 256
#define OUT_DIM 64
#define NSPLIT 4
#define BK 64
#define NIT ((NR / NSPLIT) / BK)      // 32
// 2^-1.25 * sqrt(log2(e)): qh = q*QS2 -> dot = (q.q')/sqrt(32)*log2(e); p=2^s
#define QSCALE2 0.5050114839784955f

typedef short short4v __attribute__((ext_vector_type(4)));
typedef short short8 __attribute__((ext_vector_type(8)));   // 8 bf16
typedef float f32x16 __attribute__((ext_vector_type(16)));  // 32x32 MFMA acc
typedef unsigned int u32;
typedef __attribute__((address_space(1))) const u32 gas_t;
typedef __attribute__((address_space(3))) u32 las_t;

__device__ __forceinline__ unsigned short f32_to_bf16(float f) {
    union { float f; unsigned int u; } v; v.f = f;
    unsigned int u = v.u + 0x7FFFu + ((v.u >> 16) & 1u);    // RNE
    return (unsigned short)(u >> 16);
}
__device__ __forceinline__ float exp2_fast(float x) {
#if __has_builtin(__builtin_amdgcn_exp2f)
    return __builtin_amdgcn_exp2f(x);
#else
    return exp2f(x);
#endif
}

// ---------------------------------------------------------------------------
// prep: [0,1040) zero acc+lsum | [1040,1552) qconv x4 | [1552,1568) wconv
// ---------------------------------------------------------------------------
__global__ void prep_kernel(const float* __restrict__ user,
                            const float* __restrict__ item,
                            const float* __restrict__ Wu,
                            const float* __restrict__ Wi,
                            float4* __restrict__ accz,
                            unsigned short* __restrict__ qh,
                            unsigned short* __restrict__ wbf) {
    int b = blockIdx.x, t = threadIdx.x;
    if (b < 1040) {                       // zero 4.26 MB
        accz[b * 256 + t] = make_float4(0.f, 0.f, 0.f, 0.f);
        return;
    }
    b -= 1040;
    if (b < 512) {                        // qconv: 4 floats/thread
        int i = (b * 256 + t) * 4;        // 0..524287
        int side  = i >= NR * DQ;
        int local = i - side * NR * DQ;
        const float* src = side ? item : user;
        float4 v = *(const float4*)(src + local);
        short4v o;
        o[0] = (short)f32_to_bf16(v.x * QSCALE2);
        o[1] = (short)f32_to_bf16(v.y * QSCALE2);
        o[2] = (short)f32_to_bf16(v.z * QSCALE2);
        o[3] = (short)f32_to_bf16(v.w * QSCALE2);
        *(short4v*)(qh + i) = o;
        return;
    }
    b -= 512;                             // wconv
    int g  = b * 256 + t;                 // 0..4095
    int ln = g & 31, h = (g >> 5) & 1, nt = (g >> 6) & 1;
    int kt = (g >> 7) & 3, p = (g >> 9) & 3, wm = g >> 11;
    const float* W = wm ? Wi : Wu;
    unsigned short* dst = wbf + (size_t)g * 8;
#pragma unroll
    for (int i = 0; i < 8; ++i) {
        int k = p * 64 + kt * 16 + h * 8 + i;
        dst[i] = f32_to_bf16(W[k * OUT_DIM + nt * 32 + ln]);
    }
}

// ---------------------------------------------------------------------------
// Gather via LDS transpose into PERMUTED frag-native vt (unchanged from R5;
// R5 passed with this flash<->vt layout pairing).
// ---------------------------------------------------------------------------
__global__ void gather_vt_kernel(const float* __restrict__ review,
                                 const float* __restrict__ user,
                                 const float* __restrict__ item,
                                 const int* __restrict__ adj_ur, const int* __restrict__ adj_ri,
                                 const int* __restrict__ adj_ir, const int* __restrict__ adj_ru,
                                 unsigned short* __restrict__ vt) {
    const int side = blockIdx.y;
    const int key0 = blockIdx.x * 64;
    const int t = threadIdx.x;
    __shared__ __align__(16) unsigned short T[64][264];
    const int* adjA   = side ? adj_ir : adj_ur;
    const int* adjB   = side ? adj_ru : adj_ri;
    const float* srcB = side ? user : item;
    {
        int key = t >> 2, q = t & 3;
#pragma unroll
        for (int rr = 0; rr < 2; ++rr) {
            int ss  = q * 2 + rr;
            int knb = ss >> 1, isB = ss & 1;
            int row = (isB ? adjB : adjA)[(key0 + key) * 4 + knb];
            const float4* src = (const float4*)((isB ? srcB : review) + (size_t)row * DQ);
            int dbase = knb * 64 + isB * 32;
#pragma unroll
            for (int d = 0; d < 4; ++d) {
                float4 a = src[d * 2], b2 = src[d * 2 + 1];
                short8 v;
                v[0] = (short)f32_to_bf16(a.x);  v[1] = (short)f32_to_bf16(a.y);
                v[2] = (short)f32_to_bf16(a.z);  v[3] = (short)f32_to_bf16(a.w);
                v[4] = (short)f32_to_bf16(b2.x); v[5] = (short)f32_to_bf16(b2.y);
                v[6] = (short)f32_to_bf16(b2.z); v[7] = (short)f32_to_bf16(b2.w);
                *(short8*)&T[key][dbase + d * 8] = v;
            }
        }
    }
    __syncthreads();
#pragma unroll
    for (int w8 = 0; w8 < 8; ++w8) {
        int u    = t + 256 * w8;
        int lane = u & 63;
        int ct   = (u >> 6) & 7;
        int ktl  = u >> 9;
        int ln = lane & 31, h = lane >> 5;
        int col = ct * 32 + ln;
        short8 v;
#pragma unroll
        for (int i = 0; i < 8; ++i) {
            int lkey = (i & 1) * 32 + ktl * 8 + h * 4 + (i >> 1);
            v[i] = (short)T[lkey][col];
        }
        size_t dst = (size_t)side * NR * DV
                   + ((size_t)blockIdx.x * 4 + ktl) * 4096
                   + (size_t)ct * 512 + (size_t)lane * 8;
        *(short8*)(vt + dst) = v;
    }
}

// ---------------------------------------------------------------------------
// Flash attention: 8-wave blocks, LDS-shared double-buffered V tiles.
// bx&7 = side + 2*sp (XCD-affine), rb = bx>>3 (0..31). 256 blocks x 512 thr.
// ---------------------------------------------------------------------------
__global__ __launch_bounds__(512, 2) void flash_kernel(
        const unsigned short* __restrict__ qh,
        const unsigned short* __restrict__ vt,
        const unsigned short* __restrict__ wbf,
        float* __restrict__ acc,     // [2][NR][64]
        float* __restrict__ lsum)    // [2][NR]
{
    const int bx   = blockIdx.x;
    const int side = bx & 1;
    const int sp   = (bx >> 1) & (NSPLIT - 1);
    const int rb   = bx >> 3;                  // 0..31
    const int w    = threadIdx.x >> 6;         // 0..7
    const int lane = threadIdx.x & 63;
    const int ln   = lane & 31;
    const int h    = lane >> 5;

    const int m0 = rb * 256 + w * 32;
    const unsigned short* Q  = qh + (size_t)side * NR * DQ;
    const unsigned short* VT = vt + (size_t)side * NR * DV;
    const int j_begin = sp * (NR / NSPLIT);

    __shared__ __align__(16) unsigned short Vbuf[2][16384];   // 64 KB
    __shared__ __align__(16) unsigned short Pbuf[8][32 * 72]; // 36.9 KB
    unsigned short* Pw = Pbuf[w];
    unsigned int* Pw32 = (unsigned int*)Pw;

    // stage 64-key tile t into Vbuf[b]: this wave's 4 KB slice via DMA.
    auto stage = [&](int t, int b) {
        const unsigned short* src = VT + ((size_t)(j_begin + t * BK) >> 4) * 4096
                                  + w * 2048 + lane * 8;
        unsigned short* dst = &Vbuf[b][w * 2048];
#pragma unroll
        for (int k2 = 0; k2 < 4; ++k2)
            __builtin_amdgcn_global_load_lds((gas_t*)(src + k2 * 512),
                                             (las_t*)(dst + k2 * 512), 16, 0, 0);
    };
    // kb loads for S-phase of tile at j0 (issued early, consumed later)
    auto load_kb = [&](int j0, short8* kb) {
        const unsigned short* kb0 = Q + (size_t)(j0 + ln) * DQ + h * 8;
        const unsigned short* kb1 = Q + (size_t)(j0 + 32 + ln) * DQ + h * 8;
        kb[0] = *(const short8*)(kb0);
        kb[1] = *(const short8*)(kb0 + 16);
        kb[2] = *(const short8*)(kb1);
        kb[3] = *(const short8*)(kb1 + 16);
    };

    short8 aq[2];
#pragma unroll
    for (int dh = 0; dh < 2; ++dh)
        aq[dh] = *(const short8*)(Q + (size_t)(m0 + ln) * DQ + dh * 16 + h * 8);

    f32x16 zf;
#pragma unroll
    for (int r = 0; r < 16; ++r) zf[r] = 0.f;
    f32x16 o[8];
#pragma unroll
    for (int ct = 0; ct < 8; ++ct) o[ct] = zf;
    float l_part[16];
#pragma unroll
    for (int r = 0; r < 16; ++r) l_part[r] = 0.f;

    // S-compute: S-MFMA on kb frags -> exp -> packed b32 into Pw.
    auto s_compute = [&](short8* kb, int do_wait) {
        f32x16 s0 = __builtin_amdgcn_mfma_f32_32x32x16_bf16(aq[0], kb[0], zf, 0, 0, 0);
        s0 = __builtin_amdgcn_mfma_f32_32x32x16_bf16(aq[1], kb[1], s0, 0, 0, 0);
        f32x16 s1 = __builtin_amdgcn_mfma_f32_32x32x16_bf16(aq[0], kb[2], zf, 0, 0, 0);
        s1 = __builtin_amdgcn_mfma_f32_32x32x16_bf16(aq[1], kb[3], s1, 0, 0, 0);
        if (do_wait) __builtin_amdgcn_s_waitcnt(0xC07F);  // lgkmcnt(0): ap landed
#pragma unroll
        for (int r = 0; r < 16; ++r) {
            float e0 = exp2_fast(s0[r]);
            float e1 = exp2_fast(s1[r]);
            l_part[r] += e0 + e1;
            unsigned int u0 = __builtin_bit_cast(unsigned int, e0) + 0x8000u;
            unsigned int u1 = __builtin_bit_cast(unsigned int, e1) + 0x8000u;
            unsigned int pk = __builtin_amdgcn_perm(u1, u0, 0x07060302);
            int row = (r & 3) + ((r >> 2) << 3) + h * 4;
            Pw32[row * 36 + ln] = pk;
        }
    };

    // ---- prologue: kb(0), stage tile 0, P(0) ----
    {
        short8 kb[4];
        load_kb(j_begin, kb);
        stage(0, 0);
        s_compute(kb, 0);
    }

    for (int it = 0; it < NIT; ++it) {
        __syncthreads();   // vmcnt(0)+lgkm drain: tile `it` staged, buf swap safe
        const int more = (it + 1 < NIT);
        short8 kb2[4];
        if (more) load_kb(j_begin + (it + 1) * BK, kb2);   // global, before DMA
        if (more) stage(it + 1, (it + 1) & 1);
        // preload ap frags of P(it)
        short8 ap[4];
#pragma unroll
        for (int ks = 0; ks < 4; ++ks)
            ap[ks] = *(const short8*)&Pw[ln * 72 + ks * 16 + h * 8];
        if (more) s_compute(kb2, 1);                       // builds P(it+1)

        // PV for tile it from LDS
        const unsigned short* vb = &Vbuf[it & 1][0] + (size_t)lane * 8;
#pragma unroll
        for (int ks = 0; ks < 4; ++ks) {
#pragma unroll
            for (int ct = 0; ct < 8; ++ct) {
                short8 bv = *(const short8*)(vb + ks * 4096 + ct * 512);
                o[ct] = __builtin_amdgcn_mfma_f32_32x32x16_bf16(ap[ks], bv, o[ct], 0, 0, 0);
            }
        }
    }

    // ---- l: reduce per-lane partials across 32 key-lanes of each half ----
#pragma unroll
    for (int r = 0; r < 16; ++r) {
        float v = l_part[r];
        v += __shfl_xor(v, 1);
        v += __shfl_xor(v, 2);
        v += __shfl_xor(v, 4);
        v += __shfl_xor(v, 8);
        v += __shfl_xor(v, 16);
        l_part[r] = v;
    }
    if (ln == 0) {
#pragma unroll
        for (int r = 0; r < 16; ++r) {
            int row = (r & 3) + ((r >> 2) << 3) + h * 4;
            atomicAdd(&lsum[(size_t)side * NR + m0 + row], l_part[r]);
        }
    }

    // ---- epilogue: 4 passes of 64 cols: O->bf16->LDS, proj MFMA ----
    f32x16 pp[2];
    pp[0] = zf; pp[1] = zf;
    const unsigned short* wb_base = wbf + (size_t)side * 16384;
#pragma unroll
    for (int p = 0; p < 4; ++p) {
        __builtin_amdgcn_s_waitcnt(0xC07F);
#pragma unroll
        for (int c2 = 0; c2 < 2; ++c2)
#pragma unroll
            for (int r = 0; r < 16; ++r) {
                int row = (r & 3) + ((r >> 2) << 3) + h * 4;
                Pw[row * 72 + c2 * 32 + ln] = f32_to_bf16(o[2 * p + c2][r]);
            }
#pragma unroll
        for (int kt = 0; kt < 4; ++kt) {
            short8 a = *(const short8*)&Pw[ln * 72 + kt * 16 + h * 8];
#pragma unroll
            for (int nt = 0; nt < 2; ++nt) {
                short8 bw = *(const short8*)(wb_base
                            + ((size_t)(p * 4 + kt) * 2 + nt) * 512 + (size_t)lane * 8);
                pp[nt] = __builtin_amdgcn_mfma_f32_32x32x16_bf16(a, bw, pp[nt], 0, 0, 0);
            }
        }
    }

    // ---- atomic accumulate projected partials ----
#pragma unroll
    for (int nt = 0; nt < 2; ++nt)
#pragma unroll
        for (int r = 0; r < 16; ++r) {
            int row = (r & 3) + ((r >> 2) << 3) + h * 4;
            atomicAdd(&acc[((size_t)side * NR + m0 + row) * OUT_DIM + nt * 32 + ln],
                      pp[nt][r]);
        }
}

// ---------------------------------------------------------------------------
__global__ void final_kernel(const float* __restrict__ acc,
                             const float* __restrict__ lsum,
                             float* __restrict__ out) {
    int tid = blockIdx.x * blockDim.x + threadIdx.x;
    int row = tid >> 6;
    out[tid] = fmaxf(acc[tid] / lsum[row], 0.f);
}

// ---------------------------------------------------------------------------
extern "C" void kernel_launch(void* const* d_in, const int* in_sizes, int n_in,
                              void* d_out, int out_size, void* d_ws, size_t ws_size,
                              hipStream_t stream) {
    const float* review = (const float*)d_in[0];
    const float* user   = (const float*)d_in[1];
    const float* item   = (const float*)d_in[2];
    const int* adj_ur   = (const int*)d_in[3];
    const int* adj_ri   = (const int*)d_in[4];
    const int* adj_ir   = (const int*)d_in[5];
    const int* adj_ru   = (const int*)d_in[6];
    const float* Wu     = (const float*)d_in[7];
    const float* Wi     = (const float*)d_in[8];
    float* out = (float*)d_out;

    // ws: acc | lsum | vt | qh | wbf  (~13.2 MB)
    float* acc  = (float*)d_ws;
    float* lsum = acc + (size_t)2 * NR * OUT_DIM;
    unsigned short* vt  = (unsigned short*)(lsum + 2 * NR);
    unsigned short* qh  = vt + (size_t)2 * NR * DV;
    unsigned short* wbf = qh + (size_t)2 * NR * DQ;

    prep_kernel<<<1568, 256, 0, stream>>>(user, item, Wu, Wi,
                                          (float4*)acc, qh, wbf);
    gather_vt_kernel<<<dim3(NR / 64, 2), 256, 0, stream>>>(
        review, user, item, adj_ur, adj_ri, adj_ir, adj_ru, vt);
    flash_kernel<<<2 * NSPLIT * (NR / 256), 512, 0, stream>>>(qh, vt, wbf, acc, lsum);
    final_kernel<<<2 * NR * OUT_DIM / 256, 256, 0, stream>>>(acc, lsum, out);
}